// Round 2
// baseline (3463.449 us; speedup 1.0000x reference)
//
#include <hip/hip_runtime.h>
#include <hip/hip_bf16.h>
#include <hip/hip_fp16.h>

// ---------------------------------------------------------------------------
// MPNN binding-affinity predictor. R16 = R15 (478us) +
//  - MEGA-FUSION: entire pre-readout pipeline (hist/scan/scatter+convert/
//    fold/embed/6x(PQR,agg,M3)) runs as ONE persistent kernel with a
//    hand-rolled device-scope grid barrier. Dispatches: 25 -> 3.
//    Theory: ~280us of wall time was HSA barrier-packet gaps between
//    dependent dispatches (~10us each); grid barriers cost ~2-3us.
//  - Residency by construction: __launch_bounds__(256,3) caps VGPR at 168,
//    LDS 24.6KB/block, grid=736 <= 256 CUs x 3 blocks.
// ---------------------------------------------------------------------------

#define HID 256
#define NGRP 32
constexpr int NBLK = 736;  // multiple of NGRP; <= 256 CUs * 3 blocks/CU

typedef _Float16 h8 __attribute__((ext_vector_type(8)));
typedef float f32x4 __attribute__((ext_vector_type(4)));

__device__ __forceinline__ void unpack_h8(const int4& r, float* f) {
    const __half2* h = reinterpret_cast<const __half2*>(&r);
#pragma unroll
    for (int k = 0; k < 4; ++k) {
        float2 t = __half22float2(h[k]);
        f[2 * k] = t.x;
        f[2 * k + 1] = t.y;
    }
}

__device__ __forceinline__ void unpack_h4(const int2& r, float* f) {
    const __half2* h = reinterpret_cast<const __half2*>(&r);
    float2 t0 = __half22float2(h[0]);
    float2 t1 = __half22float2(h[1]);
    f[0] = t0.x; f[1] = t0.y; f[2] = t1.x; f[3] = t1.y;
}

// async global -> LDS 16B DMA; dest wave-uniform, lane i lands at dest+16*i
__device__ __forceinline__ void gld16(const void* g, void* l) {
    __builtin_amdgcn_global_load_lds(
        (const __attribute__((address_space(1))) void*)g,
        (__attribute__((address_space(3))) void*)l, 16, 0, 0);
}

// XOR swizzle of 16B k-segments per row; fragment reads <=2-way (free)
__device__ __forceinline__ int swz(int row) { return (row + (row >> 2)) & 3; }

// ------------------------- descriptor tables -------------------------------

struct CDesc {
    const float* src;
    __half* dst;
    int Kreal, Kpad, srcN, tile0;
};
struct CTab {
    CDesc d[32];
    int nd;
};

struct FDesc { const float* U2; const __half* Wfb; __half* dst; };
struct FTab { FDesc d[22]; };

struct BDesc { float* out; const float* base; const float* v1; const float* B1;
               const float* v2; const float* B2; };

struct MegaArgs {
    const int* src; const int* dst;
    const float* atom; const float* ef; const float* emb_b;
    const float* msg_w1; const float* msg_b1; const float* msg_b2;
    const float* upd_w1; const float* upd_b1; const float* upd_b2;
    const float* r_b1; const float* r_w1;
    int* deg; int* cursor; int* bar; int* offs; int* csr_src;
    float* degf; float* bvec; float* b768;
    __half* ef8; __half* atomH; __half* w_emb;
    __half* bufX0; __half* bufX1; __half* PQR; __half* HaggH;
    __half* wPQR[6]; __half* wM3[6];
    int E, N, L, hag, tiles;
    CTab ct; FTab ft;
};

// --------------------------- grid barrier ----------------------------------
// Two-level sense-reversing barrier. bar[0..NGRP-1]=group counters,
// bar[NGRP]=global counter, bar[NGRP+1]=sense. Device-scope atomics work
// across XCDs; __threadfence() on both sides gives release/acquire cache
// semantics (wb/inv L2) equivalent to a kernel boundary.

__device__ void gbar(int* bar, int nblk, int* lsense) {
    __threadfence();       // release this block's writes device-wide
    __syncthreads();
    if (threadIdx.x == 0) {
        int s = *lsense ^ 1;
        *lsense = s;
        const int g = (int)blockIdx.x & (NGRP - 1);
        const int gsz = nblk / NGRP;
        int a = __hip_atomic_fetch_add(&bar[g], 1, __ATOMIC_ACQ_REL,
                                       __HIP_MEMORY_SCOPE_AGENT);
        if (a == gsz - 1) {
            __hip_atomic_store(&bar[g], 0, __ATOMIC_RELAXED,
                               __HIP_MEMORY_SCOPE_AGENT);
            int b = __hip_atomic_fetch_add(&bar[NGRP], 1, __ATOMIC_ACQ_REL,
                                           __HIP_MEMORY_SCOPE_AGENT);
            if (b == NGRP - 1) {
                __hip_atomic_store(&bar[NGRP], 0, __ATOMIC_RELAXED,
                                   __HIP_MEMORY_SCOPE_AGENT);
                __hip_atomic_store(&bar[NGRP + 1], s, __ATOMIC_RELEASE,
                                   __HIP_MEMORY_SCOPE_AGENT);
            }
        }
        while (__hip_atomic_load(&bar[NGRP + 1], __ATOMIC_RELAXED,
                                 __HIP_MEMORY_SCOPE_AGENT) != s)
            __builtin_amdgcn_s_sleep(1);
    }
    __syncthreads();
    __threadfence();       // acquire: invalidate stale cached lines
}

// --------------------------- phase bodies ----------------------------------

__device__ void convert_body(const CTab& tab, int bid) {
    int idx = 0;
    for (int i = 1; i < tab.nd; ++i)
        if (tab.d[i].tile0 <= bid) idx = i;
    const CDesc d = tab.d[idx];
    const int q = bid - d.tile0;
    const int ntN = d.srcN >> 6;
    const int kb = (q / ntN) * 32;
    const int nb = (q % ntN) * 64;
    const int n = nb + (threadIdx.x & 63);
    const int k0 = kb + (threadIdx.x >> 6) * 8;
    h8 v;
#pragma unroll
    for (int j = 0; j < 8; ++j) {
        int k = k0 + j;
        v[j] = (_Float16)((k < d.Kreal) ? d.src[(size_t)k * d.srcN + n] : 0.f);
    }
    *reinterpret_cast<h8*>(&d.dst[(size_t)n * d.Kpad + k0]) = v;
}

__device__ void scan_body(unsigned char* ldsraw, const int* deg, int* offs,
                          float* degf, int n) {
    int* ws = (int*)ldsraw;
    const int t = threadIdx.x;
    const int lane = t & 63;
    const int w = t >> 6;
    const int per = (n + 255) / 256;
    const int s = t * per;
    const int e = min(s + per, n);
    int sum = 0;
    for (int i = s; i < e; ++i) sum += deg[i];
    int v = sum;
#pragma unroll
    for (int off = 1; off < 64; off <<= 1) {
        int u = __shfl_up(v, off, 64);
        if (lane >= off) v += u;
    }
    if (lane == 63) ws[w] = v;
    __syncthreads();
    if (t == 0) {
        int c = 0;
#pragma unroll
        for (int i = 0; i < 4; ++i) { int x = ws[i]; ws[i] = c; c += x; }
    }
    __syncthreads();
    int run = ws[w] + v - sum;
    for (int i = s; i < e; ++i) {
        int d = deg[i];
        offs[i] = run;
        degf[i] = (float)d;
        run += d;
    }
    if (e == n) offs[n] = run;
}

__device__ void scatter_part(const MegaArgs& A, int vb) {
    int i = vb * 256 + (int)threadIdx.x;
    if (i < A.E) {
        int d = A.dst[i];
        int pos = atomicAdd(&A.cursor[d], 1);
        int idx = A.offs[d] + pos;
        A.csr_src[idx] = A.src[i];
        const float* s6 = A.ef + (size_t)i * 6;
        unsigned short h[8];
#pragma unroll
        for (int j = 0; j < 6; ++j) h[j] = __half_as_ushort(__float2half_rn(s6[j]));
        h[6] = 0; h[7] = 0;
        int4 pk;
        pk.x = (int)(h[0] | ((unsigned)h[1] << 16));
        pk.y = (int)(h[2] | ((unsigned)h[3] << 16));
        pk.z = (int)(h[4] | ((unsigned)h[5] << 16));
        pk.w = (int)(h[6] | ((unsigned)h[7] << 16));
        *reinterpret_cast<int4*>(A.ef8 + (size_t)idx * 8) = pk;
    }
}

#define ASTR 40

__device__ void fold_tile(unsigned char* ldsraw, const FDesc& dd, int t4) {
    _Float16* Ah = (_Float16*)ldsraw;                       // 64*ASTR halves
    _Float16* Bh = (_Float16*)(ldsraw + 64 * ASTR * 2);     // 64*ASTR halves
    const int rowBase = (t4 >> 2) * 64;  // n-block
    const int colBase = (t4 & 3) * 64;   // k-block

    const int tid = threadIdx.x;
    const int lane = tid & 63;
    const int wave = tid >> 6;
    const int waveM = (wave >> 1) * 32;
    const int waveN = (wave & 1) * 32;
    const int m0 = lane & 15;
    const int quad = lane >> 4;
    const int sr = tid >> 2;
    const int sseg = tid & 3;

    const f32x4 z = {0.f, 0.f, 0.f, 0.f};
    f32x4 acc[2][2] = {{z, z}, {z, z}};

    for (int kb = 0; kb < 256; kb += 32) {
        {
            size_t off = (size_t)(rowBase + sr) * 256 + kb + sseg * 8;
            *reinterpret_cast<int4*>(&Ah[sr * ASTR + sseg * 8]) =
                *reinterpret_cast<const int4*>(&dd.Wfb[off]);
        }
        {
            const float* Bp = dd.U2 + (size_t)(colBase + sr) * 256 + kb + sseg * 8;
            float4 u0 = *reinterpret_cast<const float4*>(Bp);
            float4 u1 = *reinterpret_cast<const float4*>(Bp + 4);
            h8 v;
            v[0] = (_Float16)u0.x; v[1] = (_Float16)u0.y;
            v[2] = (_Float16)u0.z; v[3] = (_Float16)u0.w;
            v[4] = (_Float16)u1.x; v[5] = (_Float16)u1.y;
            v[6] = (_Float16)u1.z; v[7] = (_Float16)u1.w;
            *reinterpret_cast<h8*>(&Bh[sr * ASTR + sseg * 8]) = v;
        }
        __syncthreads();

        const h8 a0 = *reinterpret_cast<const h8*>(&Ah[(waveM + m0) * ASTR + quad * 8]);
        const h8 a1 = *reinterpret_cast<const h8*>(&Ah[(waveM + 16 + m0) * ASTR + quad * 8]);
        const h8 b0 = *reinterpret_cast<const h8*>(&Bh[(waveN + m0) * ASTR + quad * 8]);
        const h8 b1 = *reinterpret_cast<const h8*>(&Bh[(waveN + 16 + m0) * ASTR + quad * 8]);

        acc[0][0] = __builtin_amdgcn_mfma_f32_16x16x32_f16(a0, b0, acc[0][0], 0, 0, 0);
        acc[0][1] = __builtin_amdgcn_mfma_f32_16x16x32_f16(a0, b1, acc[0][1], 0, 0, 0);
        acc[1][0] = __builtin_amdgcn_mfma_f32_16x16x32_f16(a1, b0, acc[1][0], 0, 0, 0);
        acc[1][1] = __builtin_amdgcn_mfma_f32_16x16x32_f16(a1, b1, acc[1][1], 0, 0, 0);

        __syncthreads();
    }

#pragma unroll
    for (int tm = 0; tm < 2; ++tm)
#pragma unroll
        for (int reg = 0; reg < 4; ++reg) {
            int n = rowBase + waveM + tm * 16 + quad * 4 + reg;
#pragma unroll
            for (int tn = 0; tn < 2; ++tn) {
                int k = colBase + waveN + tn * 16 + m0;
                dd.dst[(size_t)n * 256 + k] = __float2half_rn(acc[tm][tn][reg]);
            }
        }
}

__device__ BDesc make_bdesc(const MegaArgs& A, int i) {
    BDesc r;
    r.out = nullptr; r.base = nullptr; r.v1 = nullptr; r.B1 = nullptr;
    r.v2 = nullptr; r.B2 = nullptr;
    if (i == 30) {
        r.out = A.bvec + (size_t)18 * 256;
        r.base = A.r_b1;
        r.v1 = A.upd_b2 + (size_t)5 * 256;
        r.B1 = A.r_w1;
        return r;
    }
    const int l = i / 5, s = i % 5;
    const float* ub2p = (l > 0) ? A.upd_b2 + (size_t)(l - 1) * 256 : nullptr;
    switch (s) {
        case 0:
            r.out = A.b768 + (size_t)l * 768 + 256;
            r.base = A.msg_b1 + (size_t)l * 256;
            r.v1 = ub2p; r.B1 = A.msg_w1 + (size_t)l * 518 * 256;
            r.v2 = ub2p; r.B2 = A.msg_w1 + (size_t)l * 518 * 256 + 256 * 256;
            break;
        case 1:
            r.out = A.b768 + (size_t)l * 768;
            break;
        case 2:
            r.out = A.b768 + (size_t)l * 768 + 512;
            break;
        case 3:
            r.out = A.bvec + (size_t)(6 + l) * 256;
            r.base = A.upd_b1 + (size_t)l * 256;
            r.v1 = ub2p; r.B1 = A.upd_w1 + (size_t)l * 512 * 256;
            break;
        case 4:
            r.out = A.bvec + (size_t)(12 + l) * 256;
            r.v2 = A.msg_b2 + (size_t)l * 256;
            r.B2 = A.upd_w1 + (size_t)l * 512 * 256 + 256 * 256;
            break;
    }
    return r;
}

__device__ void fold_bias_body(const MegaArgs& A, int i) {
    const BDesc d = make_bdesc(A, i);
    const int j = threadIdx.x;
    float acc = d.base ? d.base[j] : 0.f;
    if (d.v1)
        for (int k = 0; k < 256; ++k) acc = fmaf(d.v1[k], d.B1[(size_t)k * 256 + j], acc);
    if (d.v2)
        for (int k = 0; k < 256; ++k) acc = fmaf(d.v2[k], d.B2[(size_t)k * 256 + j], acc);
    d.out[j] = acc;
}

// ------------------------------ MFMA GEMM tile -----------------------------
// C = act( A@W + bias + rowscale.*bias2 + addend ), fp16 in/out, fp32 acc.
// Tile 64 x (TN*32), BK=32, 4 waves 2x2. Double-buffered: raw s_barrier +
// manual vmcnt. NOTE: leftover epilogue stores from a previous tile only
// deepen the vmcnt FIFO ahead of our loads (stores are older), so the
// vmcnt(N) waits remain correct in a multi-tile loop.

template <int TN>
__device__ void gemm_tile(
    unsigned char* lds, int bx, int by,
    const __half* __restrict__ A, int lda,
    const __half* __restrict__ W, int K,
    const float* __restrict__ bias, const float* __restrict__ bias2,
    const float* __restrict__ rowscale,
    const __half* __restrict__ addend, int astride,
    __half* __restrict__ C, int M, int Nc, int do_relu) {
    constexpr int BUF = 4096 + TN * 2048;  // bytes per buffer set

    const int tid = threadIdx.x;
    const int lane = tid & 63;
    const int wave = tid >> 6;
    const int m0 = lane & 15;
    const int quad = lane >> 4;
    const int waveM = (wave >> 1) * 32;
    const int waveN = (wave & 1) * (TN * 16);
    const int rowBase = bx * 64;
    const int colBase = by * (TN * 32);

    const int sa_r = tid >> 2;
    const int sa_ks = (tid & 3) ^ swz(sa_r);
    const int sa_row = min(rowBase + sa_r, M - 1);
    const int sb_r1 = sa_r + 64;
    const int sb_ks1 = (tid & 3) ^ swz(sb_r1);

    int aoff[2], boff[TN];
#pragma unroll
    for (int tm = 0; tm < 2; ++tm) {
        int r = waveM + tm * 16 + m0;
        aoff[tm] = ((r << 2) + (quad ^ swz(r))) << 4;
    }
#pragma unroll
    for (int tn = 0; tn < TN; ++tn) {
        int r = waveN + tn * 16 + m0;
        boff[tn] = 4096 + (((r << 2) + (quad ^ swz(r))) << 4);
    }

    const f32x4 z = {0.f, 0.f, 0.f, 0.f};
    f32x4 acc[2][TN];
#pragma unroll
    for (int tm = 0; tm < 2; ++tm)
#pragma unroll
        for (int tn = 0; tn < TN; ++tn) acc[tm][tn] = z;

    const __half* ga = A + (size_t)sa_row * lda + sa_ks * 8;
    const __half* gb0 = W + (size_t)(colBase + sa_r) * K + sa_ks * 8;
    const __half* gb1 = W + (size_t)(colBase + sb_r1) * K + sb_ks1 * 8;

    auto issue = [&](int p, int kb) {
        unsigned char* base = lds + p * BUF;
        gld16(ga + kb, base + wave * 1024);
        gld16(gb0 + kb, base + 4096 + wave * 1024);
        if constexpr (TN == 4) gld16(gb1 + kb, base + 8192 + wave * 1024);
    };

    issue(0, 0);
    int p = 0;
    for (int kb = 0; kb < K; kb += 32) {
        const bool has_next = (kb + 32 < K);
        if (has_next) issue(p ^ 1, kb + 32);
        if (has_next) {
            if constexpr (TN == 4)
                asm volatile("s_waitcnt vmcnt(3)" ::: "memory");
            else
                asm volatile("s_waitcnt vmcnt(2)" ::: "memory");
        } else {
            asm volatile("s_waitcnt vmcnt(0)" ::: "memory");
        }
        asm volatile("s_barrier" ::: "memory");

        const unsigned char* base = lds + p * BUF;
        h8 ah[2], bh[TN];
#pragma unroll
        for (int tm = 0; tm < 2; ++tm)
            ah[tm] = *reinterpret_cast<const h8*>(base + aoff[tm]);
#pragma unroll
        for (int tn = 0; tn < TN; ++tn)
            bh[tn] = *reinterpret_cast<const h8*>(base + boff[tn]);
#pragma unroll
        for (int tm = 0; tm < 2; ++tm)
#pragma unroll
            for (int tn = 0; tn < TN; ++tn)
                acc[tm][tn] = __builtin_amdgcn_mfma_f32_16x16x32_f16(
                    ah[tm], bh[tn], acc[tm][tn], 0, 0, 0);
        asm volatile("s_waitcnt lgkmcnt(0)" ::: "memory");
        asm volatile("s_barrier" ::: "memory");
        p ^= 1;
    }

    // epilogue
    float cb[TN], db[TN];
    int col[TN];
#pragma unroll
    for (int tn = 0; tn < TN; ++tn) {
        col[tn] = colBase + waveN + tn * 16 + m0;
        cb[tn] = bias ? bias[col[tn]] : 0.f;
        db[tn] = bias2 ? bias2[col[tn]] : 0.f;
    }
#pragma unroll
    for (int tm = 0; tm < 2; ++tm) {
#pragma unroll
        for (int reg = 0; reg < 4; ++reg) {
            int row = rowBase + waveM + tm * 16 + quad * 4 + reg;
            if (row >= M) continue;
            float rs = rowscale ? rowscale[row] : 0.0f;
#pragma unroll
            for (int tn = 0; tn < TN; ++tn) {
                float v = acc[tm][tn][reg] + cb[tn] + rs * db[tn];
                if (addend)
                    v += __half2float(addend[(size_t)row * astride + col[tn]]);
                if (do_relu) v = fmaxf(v, 0.f);
                C[(size_t)row * Nc + col[tn]] = __float2half_rn(v);
            }
        }
    }
}

// ------------------------------ mega kernel --------------------------------

__global__ __launch_bounds__(256, 3) void mega_kernel(MegaArgs A, int nblk) {
    __shared__ __align__(16) unsigned char lds[2 * (4096 + 4 * 2048)];
    int lsense = 0;
    const int bid = blockIdx.x;
    const int tid = threadIdx.x;
    const int mblk = (A.N + 63) / 64;

    // ---- P1: hist (deg atomics) + atomH fp16 convert + weight converts ----
    {
        const int histB = (A.hag + 255) / 256;
        const int NV = histB + A.tiles;
        for (int vb = bid; vb < NV; vb += nblk) {
            if (vb < histB) {
                int i = vb * 256 + tid;
                if (i < A.E) atomicAdd(&A.deg[A.dst[i]], 1);
                if (i < A.N * 8) {
                    int r = i >> 3, seg = i & 7;
                    h8 v;
#pragma unroll
                    for (int j = 0; j < 8; ++j) {
                        int c = seg * 8 + j;
                        v[j] = (_Float16)((c < 62) ? A.atom[(size_t)r * 62 + c] : 0.f);
                    }
                    *reinterpret_cast<h8*>(&A.atomH[(size_t)r * 64 + seg * 8]) = v;
                }
            } else {
                convert_body(A.ct, vb - histB);
            }
        }
    }
    gbar(A.bar, nblk, &lsense);

    // ---- P2: CSR offset scan (block 0 only) ----
    if (bid == 0) scan_body(lds, A.deg, A.offs, A.degf, A.N);
    gbar(A.bar, nblk, &lsense);

    // ---- P3: scatter (CSR fill + ef pack) + fold GEMMs + bias vecs + embed ----
    {
        const int sB = (A.E + 255) / 256;
        const int fgB = 22 * 16;
        const int fbB = 31;
        const int embB = mblk * 4;
        const int NV = sB + fgB + fbB + embB;
        for (int vb = bid; vb < NV; vb += nblk) {
            if (vb < sB) {
                scatter_part(A, vb);
            } else if (vb < sB + fgB) {
                int q = vb - sB;
                fold_tile(lds, A.ft.d[q >> 4], q & 15);
            } else if (vb < sB + fgB + fbB) {
                fold_bias_body(A, vb - sB - fgB);
            } else {
                int q = vb - sB - fgB - fbB;
                gemm_tile<2>(lds, q % mblk, q / mblk, A.atomH, 64, A.w_emb, 64,
                             A.emb_b, nullptr, nullptr, nullptr, 0,
                             A.bufX0, A.N, HID, 0);
            }
        }
    }
    gbar(A.bar, nblk, &lsense);

    // ---- layers ----
    __half* Up = A.bufX0;
    __half* Un = A.bufX1;
    for (int l = 0; l < A.L; ++l) {
        // PQR = Up @ [M1a|M1b|M2] + [0|bagg|0]
        {
            const int NV = mblk * 6;
            for (int vb = bid; vb < NV; vb += nblk)
                gemm_tile<4>(lds, vb % mblk, vb / mblk, Up, HID, A.wPQR[l], HID,
                             A.b768 + (size_t)l * 768, nullptr, nullptr,
                             nullptr, 0, A.PQR, A.N, 768, 0);
        }
        gbar(A.bar, nblk, &lsense);

        // aggregate: Hagg[v] = sum_e relu(P[s] + Q[v] + ef @ W1c)
        {
            const float* W1c = A.msg_w1 + (size_t)l * 518 * 256 + 512 * 256;
            const int wave = tid >> 6;
            const int lane = tid & 63;
            const int ch = lane * 4;
            float wc[6][4];
#pragma unroll
            for (int k = 0; k < 6; ++k) {
                float4 w0 = *reinterpret_cast<const float4*>(W1c + k * HID + ch);
                wc[k][0] = w0.x; wc[k][1] = w0.y; wc[k][2] = w0.z; wc[k][3] = w0.w;
            }
            const int NV = (A.N + 3) / 4;
            for (int vb = bid; vb < NV; vb += nblk) {
                const int node = vb * 4 + wave;
                if (node >= A.N) continue;
                float qb[4];
                unpack_h4(*reinterpret_cast<const int2*>(
                              A.PQR + (size_t)node * 768 + 256 + ch), qb);
                float acc[4] = {0.f, 0.f, 0.f, 0.f};

                auto fma_edge = [&](const int2& praw, const int4& eraw) {
                    float p[4], e[8];
                    unpack_h4(praw, p);
                    unpack_h8(eraw, e);
#pragma unroll
                    for (int i = 0; i < 4; ++i) {
                        float h = p[i] + qb[i];
                        h = fmaf(e[0], wc[0][i], h);
                        h = fmaf(e[1], wc[1][i], h);
                        h = fmaf(e[2], wc[2][i], h);
                        h = fmaf(e[3], wc[3][i], h);
                        h = fmaf(e[4], wc[4][i], h);
                        h = fmaf(e[5], wc[5][i], h);
                        acc[i] += fmaxf(h, 0.f);
                    }
                };

                const int beg = A.offs[node];
                const int end = A.offs[node + 1];
                int j = beg;
                while (j + 6 <= end) {
                    int s0 = A.csr_src[j];
                    int s1 = A.csr_src[j + 1];
                    int s2 = A.csr_src[j + 2];
                    int s3 = A.csr_src[j + 3];
                    int s4 = A.csr_src[j + 4];
                    int s5 = A.csr_src[j + 5];
                    int4 e0 = *reinterpret_cast<const int4*>(A.ef8 + (size_t)j * 8);
                    int4 e1 = *reinterpret_cast<const int4*>(A.ef8 + (size_t)(j + 1) * 8);
                    int4 e2 = *reinterpret_cast<const int4*>(A.ef8 + (size_t)(j + 2) * 8);
                    int4 e3 = *reinterpret_cast<const int4*>(A.ef8 + (size_t)(j + 3) * 8);
                    int4 e4 = *reinterpret_cast<const int4*>(A.ef8 + (size_t)(j + 4) * 8);
                    int4 e5 = *reinterpret_cast<const int4*>(A.ef8 + (size_t)(j + 5) * 8);
                    int2 p0 = *reinterpret_cast<const int2*>(A.PQR + (size_t)s0 * 768 + ch);
                    int2 p1 = *reinterpret_cast<const int2*>(A.PQR + (size_t)s1 * 768 + ch);
                    int2 p2 = *reinterpret_cast<const int2*>(A.PQR + (size_t)s2 * 768 + ch);
                    int2 p3 = *reinterpret_cast<const int2*>(A.PQR + (size_t)s3 * 768 + ch);
                    int2 p4 = *reinterpret_cast<const int2*>(A.PQR + (size_t)s4 * 768 + ch);
                    int2 p5 = *reinterpret_cast<const int2*>(A.PQR + (size_t)s5 * 768 + ch);
                    fma_edge(p0, e0);
                    fma_edge(p1, e1);
                    fma_edge(p2, e2);
                    fma_edge(p3, e3);
                    fma_edge(p4, e4);
                    fma_edge(p5, e5);
                    j += 6;
                }
                while (j + 2 <= end) {
                    int s0 = A.csr_src[j];
                    int s1 = A.csr_src[j + 1];
                    int4 e0 = *reinterpret_cast<const int4*>(A.ef8 + (size_t)j * 8);
                    int4 e1 = *reinterpret_cast<const int4*>(A.ef8 + (size_t)(j + 1) * 8);
                    int2 p0 = *reinterpret_cast<const int2*>(A.PQR + (size_t)s0 * 768 + ch);
                    int2 p1 = *reinterpret_cast<const int2*>(A.PQR + (size_t)s1 * 768 + ch);
                    fma_edge(p0, e0);
                    fma_edge(p1, e1);
                    j += 2;
                }
                if (j < end) {
                    int s = A.csr_src[j];
                    int4 e = *reinterpret_cast<const int4*>(A.ef8 + (size_t)j * 8);
                    int2 pw = *reinterpret_cast<const int2*>(A.PQR + (size_t)s * 768 + ch);
                    fma_edge(pw, e);
                }

                unsigned short hs[4];
#pragma unroll
                for (int i = 0; i < 4; ++i)
                    hs[i] = __half_as_ushort(__float2half_rn(acc[i]));
                int2 pk;
                pk.x = (int)(hs[0] | ((unsigned)hs[1] << 16));
                pk.y = (int)(hs[2] | ((unsigned)hs[3] << 16));
                *reinterpret_cast<int2*>(A.HaggH + (size_t)node * HID + ch) = pk;
            }
        }
        gbar(A.bar, nblk, &lsense);

        // U_next = relu(Hagg @ M3 + b + deg.*b2 + R)
        {
            const int NV = mblk * 4;
            for (int vb = bid; vb < NV; vb += nblk)
                gemm_tile<2>(lds, vb % mblk, vb / mblk, A.HaggH, HID, A.wM3[l], HID,
                             A.bvec + (size_t)(6 + l) * 256,
                             A.bvec + (size_t)(12 + l) * 256, A.degf,
                             A.PQR + 512, 768, Un, A.N, HID, 1);
        }
        gbar(A.bar, nblk, &lsense);

        __half* t = Up; Up = Un; Un = t;
    }
}

// --------------------------- fused readout ---------------------------------
// h1 = relu(U5@wF + cbF) -> LDS (stride 272 halves); h2 = relu(h1@wR2 + bR2);
// s += h2 . w3 per row; block reduce; atomicAdd; done-counter finalize.

__global__ __launch_bounds__(256) void readout_kernel(
    const __half* __restrict__ U5, const __half* __restrict__ wF,
    const float* __restrict__ cbF, const __half* __restrict__ wR2,
    const float* __restrict__ bR2, const float* __restrict__ w3,
    const float* __restrict__ b3, float* __restrict__ accum,
    int* __restrict__ done, float* __restrict__ outp, int M, int nblocks) {
    __shared__ __align__(16) unsigned char lds[24576 + 64 * 272 * 2];
    _Float16* h1 = (_Float16*)(lds + 24576);

    const int tid = threadIdx.x;
    const int lane = tid & 63;
    const int wave = tid >> 6;
    const int m0 = lane & 15;
    const int quad = lane >> 4;
    const int waveM = (wave >> 1) * 32;
    const int waveN = (wave & 1) * 64;
    const int rowBase = blockIdx.x * 64;

    const int sa_r = tid >> 2;
    const int sa_ks = (tid & 3) ^ swz(sa_r);
    const int sa_row = min(rowBase + sa_r, M - 1);
    const int sb_r1 = sa_r + 64;
    const int sb_ks1 = (tid & 3) ^ swz(sb_r1);

    int aoff[2], boff[4];
#pragma unroll
    for (int tm = 0; tm < 2; ++tm) {
        int r = waveM + tm * 16 + m0;
        aoff[tm] = ((r << 2) + (quad ^ swz(r))) << 4;
    }
#pragma unroll
    for (int tn = 0; tn < 4; ++tn) {
        int r = waveN + tn * 16 + m0;
        boff[tn] = (((r << 2) + (quad ^ swz(r))) << 4);
    }

    constexpr int BUF = 4096 + 4 * 2048;
    const f32x4 z = {0.f, 0.f, 0.f, 0.f};

    for (int half = 0; half < 2; ++half) {
        const __half* W = wF + (size_t)(half * 128) * 256;
        f32x4 acc[2][4] = {{z, z, z, z}, {z, z, z, z}};
        const __half* ga = U5 + (size_t)sa_row * 256 + sa_ks * 8;
        const __half* gb0 = W + (size_t)sa_r * 256 + sa_ks * 8;
        const __half* gb1 = W + (size_t)sb_r1 * 256 + sb_ks1 * 8;

        auto issue = [&](int p, int kb) {
            unsigned char* base = lds + p * BUF;
            gld16(ga + kb, base + wave * 1024);
            gld16(gb0 + kb, base + 4096 + wave * 1024);
            gld16(gb1 + kb, base + 8192 + wave * 1024);
        };
        issue(0, 0);
        int p = 0;
        for (int kb = 0; kb < 256; kb += 32) {
            const bool has_next = (kb + 32 < 256);
            if (has_next) issue(p ^ 1, kb + 32);
            if (has_next) asm volatile("s_waitcnt vmcnt(3)" ::: "memory");
            else asm volatile("s_waitcnt vmcnt(0)" ::: "memory");
            asm volatile("s_barrier" ::: "memory");
            const unsigned char* base = lds + p * BUF;
            h8 ah[2], bh[4];
#pragma unroll
            for (int tm = 0; tm < 2; ++tm)
                ah[tm] = *reinterpret_cast<const h8*>(base + aoff[tm]);
#pragma unroll
            for (int tn = 0; tn < 4; ++tn)
                bh[tn] = *reinterpret_cast<const h8*>(base + 4096 + boff[tn]);
#pragma unroll
            for (int tm = 0; tm < 2; ++tm)
#pragma unroll
                for (int tn = 0; tn < 4; ++tn)
                    acc[tm][tn] = __builtin_amdgcn_mfma_f32_16x16x32_f16(
                        ah[tm], bh[tn], acc[tm][tn], 0, 0, 0);
            asm volatile("s_waitcnt lgkmcnt(0)" ::: "memory");
            asm volatile("s_barrier" ::: "memory");
            p ^= 1;
        }
#pragma unroll
        for (int tm = 0; tm < 2; ++tm)
#pragma unroll
            for (int reg = 0; reg < 4; ++reg) {
                int r = waveM + tm * 16 + quad * 4 + reg;
#pragma unroll
                for (int tn = 0; tn < 4; ++tn) {
                    int c = half * 128 + waveN + tn * 16 + m0;
                    float v = acc[tm][tn][reg] + cbF[c];
                    h1[r * 272 + c] = (_Float16)fmaxf(v, 0.f);
                }
            }
        __syncthreads();
    }

    f32x4 acc2[2][4] = {{z, z, z, z}, {z, z, z, z}};
    auto issueB = [&](int p, int kb) {
        unsigned char* base = lds + p * 8192;
        gld16(wR2 + (size_t)sa_r * 256 + sa_ks * 8 + kb, base + wave * 1024);
        gld16(wR2 + (size_t)sb_r1 * 256 + sb_ks1 * 8 + kb, base + 4096 + wave * 1024);
    };
    issueB(0, 0);
    int p = 0;
    for (int kb = 0; kb < 256; kb += 32) {
        const bool has_next = (kb + 32 < 256);
        if (has_next) issueB(p ^ 1, kb + 32);
        if (has_next) asm volatile("s_waitcnt vmcnt(2)" ::: "memory");
        else asm volatile("s_waitcnt vmcnt(0)" ::: "memory");
        asm volatile("s_barrier" ::: "memory");
        const unsigned char* base = lds + p * 8192;
        h8 ah[2], bh[4];
#pragma unroll
        for (int tm = 0; tm < 2; ++tm)
            ah[tm] = *reinterpret_cast<const h8*>(
                &h1[(waveM + tm * 16 + m0) * 272 + kb + quad * 8]);
#pragma unroll
        for (int tn = 0; tn < 4; ++tn)
            bh[tn] = *reinterpret_cast<const h8*>(base + boff[tn]);
#pragma unroll
        for (int tm = 0; tm < 2; ++tm)
#pragma unroll
            for (int tn = 0; tn < 4; ++tn)
                acc2[tm][tn] = __builtin_amdgcn_mfma_f32_16x16x32_f16(
                    ah[tm], bh[tn], acc2[tm][tn], 0, 0, 0);
        asm volatile("s_waitcnt lgkmcnt(0)" ::: "memory");
        asm volatile("s_barrier" ::: "memory");
        p ^= 1;
    }

    float s = 0.f;
#pragma unroll
    for (int tm = 0; tm < 2; ++tm)
#pragma unroll
        for (int reg = 0; reg < 4; ++reg) {
            int row = rowBase + waveM + tm * 16 + quad * 4 + reg;
            if (row >= M) continue;
#pragma unroll
            for (int tn = 0; tn < 4; ++tn) {
                int c = waveN + tn * 16 + m0;
                float v = acc2[tm][tn][reg] + bR2[c];
                s += fmaxf(v, 0.f) * w3[c];
            }
        }
    __syncthreads();
    float* red = (float*)lds;
    red[tid] = s;
    __syncthreads();
    for (int off = 128; off > 0; off >>= 1) {
        if (tid < off) red[tid] += red[tid + off];
        __syncthreads();
    }
    if (tid == 0) {
        atomicAdd(accum, red[0]);
        __threadfence();
        int old = atomicAdd(done, 1);
        if (old == nblocks - 1) {
            float tot = atomicAdd(accum, 0.0f);
            outp[0] = tot / (float)M + b3[0];
        }
    }
}

// ------------------------------- driver ------------------------------------

extern "C" void kernel_launch(void* const* d_in, const int* in_sizes, int n_in,
                              void* d_out, int out_size, void* d_ws, size_t ws_size,
                              hipStream_t stream) {
    const float* atom   = (const float*)d_in[0];
    const int*   eidx   = (const int*)d_in[1];
    const float* ef     = (const float*)d_in[2];
    const float* emb_w  = (const float*)d_in[3];
    const float* emb_b  = (const float*)d_in[4];
    const float* msg_w1 = (const float*)d_in[5];
    const float* msg_b1 = (const float*)d_in[6];
    const float* msg_w2 = (const float*)d_in[7];
    const float* msg_b2 = (const float*)d_in[8];
    const float* upd_w1 = (const float*)d_in[9];
    const float* upd_b1 = (const float*)d_in[10];
    const float* upd_w2 = (const float*)d_in[11];
    const float* upd_b2 = (const float*)d_in[12];
    const float* r_w1   = (const float*)d_in[13];
    const float* r_b1   = (const float*)d_in[14];
    const float* r_w2   = (const float*)d_in[15];
    const float* r_b2   = (const float*)d_in[16];
    const float* r_w3   = (const float*)d_in[17];
    const float* r_b3   = (const float*)d_in[18];

    const int N = in_sizes[0] / 62;
    const int E = in_sizes[1] / 2;
    const int L = in_sizes[5] / (518 * 256);
    const int* src = eidx;
    const int* dst = eidx + E;

    char* wp = (char*)d_ws;
    auto alloc = [&](size_t bytes) -> void* {
        void* p = (void*)wp;
        wp += (bytes + 255) & ~(size_t)255;
        return p;
    };
    int*   deg     = (int*)alloc((size_t)N * 4);
    int*   cursor  = (int*)alloc((size_t)N * 4);
    float* accum   = (float*)alloc(256);
    int*   done    = (int*)((char*)accum + 16);
    int*   bar     = (int*)alloc(512);
    size_t zero_bytes = (size_t)((char*)bar + 512 - (char*)d_ws);
    float* degf    = (float*)alloc((size_t)N * 4);
    int*   offs    = (int*)alloc((size_t)(N + 1) * 4);
    int*   csr_src = (int*)alloc((size_t)E * 4);
    __half* ef8    = (__half*)alloc((size_t)E * 8 * 2);

    const int SQ_P = 256 * 256;
    __half* w_emb = (__half*)alloc((size_t)256 * 64 * 2);
    __half* w_r2  = (__half*)alloc((size_t)128 * 256 * 2);
    __half* wF    = (__half*)alloc((size_t)SQ_P * 2);
    __half *wPQR[6], *wM3_[6];
    for (int l = 0; l < L; ++l) {
        wPQR[l] = (__half*)alloc((size_t)768 * 256 * 2);
        wM3_[l] = (__half*)alloc((size_t)SQ_P * 2);
    }
    __half* fb[22];
    for (int i = 0; i < 22; ++i) fb[i] = (__half*)alloc((size_t)SQ_P * 2);
    float* bvec = (float*)alloc((size_t)19 * 256 * 4);
    float* b768 = (float*)alloc((size_t)L * 768 * 4);

    __half* atomH = (__half*)alloc((size_t)N * 64 * 2);
    __half* bufX0 = (__half*)alloc((size_t)N * HID * 2);
    __half* bufX1 = (__half*)alloc((size_t)N * HID * 2);
    __half* PQR   = (__half*)alloc((size_t)N * 768 * 2);
    __half* HaggH = (__half*)alloc((size_t)N * HID * 2);

    hipMemsetAsync(d_ws, 0, zero_bytes, stream);

    // ---- convert descriptors ----
    MegaArgs MA;
    int nd = 0, tiles = 0;
    auto addDesc = [&](const float* s, __half* dh, int Kreal, int Kpad, int srcN) {
        MA.ct.d[nd] = {s, dh, Kreal, Kpad, srcN, tiles};
        tiles += (Kpad / 32) * (srcN / 64);
        ++nd;
    };
    addDesc(emb_w, w_emb, 62, 64, 256);
    addDesc(msg_w1, wPQR[0], 256, 256, 256);
    addDesc(msg_w1 + 256 * 256, wPQR[0] + SQ_P, 256, 256, 256);
    addDesc(upd_w1, wPQR[0] + 2 * SQ_P, 256, 256, 256);
    addDesc(r_w2, w_r2, 256, 256, 128);
    for (int l = 1; l < L; ++l) {
        addDesc(msg_w1 + (size_t)l * 518 * 256,             fb[l - 1], 256, 256, 256);
        addDesc(msg_w1 + (size_t)l * 518 * 256 + 256 * 256, fb[4 + l], 256, 256, 256);
        addDesc(upd_w1 + (size_t)l * 512 * 256,             fb[9 + l], 256, 256, 256);
    }
    for (int l = 0; l < L; ++l)
        addDesc(upd_w1 + (size_t)l * 512 * 256 + 256 * 256, fb[15 + l], 256, 256, 256);
    addDesc(r_w1, fb[21], 256, 256, 256);
    MA.ct.nd = nd;

    // ---- fold GEMM descriptors ----
    for (int l = 1; l < L; ++l) {
        const float* U2p = upd_w2 + (size_t)(l - 1) * SQ_P;
        MA.ft.d[l - 1] = {U2p, fb[l - 1], wPQR[l]};
        MA.ft.d[4 + l] = {U2p, fb[4 + l], wPQR[l] + SQ_P};
        MA.ft.d[9 + l] = {U2p, fb[9 + l], wPQR[l] + 2 * SQ_P};
    }
    for (int l = 0; l < L; ++l)
        MA.ft.d[15 + l] = {msg_w2 + (size_t)l * SQ_P, fb[15 + l], wM3_[l]};
    MA.ft.d[21] = {upd_w2 + (size_t)5 * SQ_P, fb[21], wF};

    MA.src = src; MA.dst = dst;
    MA.atom = atom; MA.ef = ef; MA.emb_b = emb_b;
    MA.msg_w1 = msg_w1; MA.msg_b1 = msg_b1; MA.msg_b2 = msg_b2;
    MA.upd_w1 = upd_w1; MA.upd_b1 = upd_b1; MA.upd_b2 = upd_b2;
    MA.r_b1 = r_b1; MA.r_w1 = r_w1;
    MA.deg = deg; MA.cursor = cursor; MA.bar = bar; MA.offs = offs;
    MA.csr_src = csr_src;
    MA.degf = degf; MA.bvec = bvec; MA.b768 = b768;
    MA.ef8 = ef8; MA.atomH = atomH; MA.w_emb = w_emb;
    MA.bufX0 = bufX0; MA.bufX1 = bufX1; MA.PQR = PQR; MA.HaggH = HaggH;
    for (int l = 0; l < 6; ++l) { MA.wPQR[l] = wPQR[l % (L > 0 ? L : 1)]; MA.wM3[l] = wM3_[l % (L > 0 ? L : 1)]; }
    for (int l = 0; l < L; ++l) { MA.wPQR[l] = wPQR[l]; MA.wM3[l] = wM3_[l]; }
    MA.E = E; MA.N = N; MA.L = L;
    MA.hag = max(E, N * 8);
    MA.tiles = tiles;

    mega_kernel<<<NBLK, 256, 0, stream>>>(MA, NBLK);

    const int mblk = (N + 63) / 64;
    __half* Ufin = (L & 1) ? bufX1 : bufX0;
    readout_kernel<<<mblk, 256, 0, stream>>>(
        Ufin, wF, bvec + (size_t)18 * 256, w_r2, r_b2, r_w3, r_b3,
        accum, done, (float*)d_out, N, mblk);
}

// Round 3
// 446.635 us; speedup vs baseline: 7.7545x; 7.7545x over previous
//
#include <hip/hip_runtime.h>
#include <hip/hip_bf16.h>
#include <hip/hip_fp16.h>

// ---------------------------------------------------------------------------
// MPNN binding-affinity predictor. R17 = R15 (478us, mega-fusion reverted) +
//  - M2 folded into M3 as K-concat: U_next = relu([Hagg|U]@[wM3;wR]+b+deg.*b2)
//    K=512 dual-source A staging. PQR GEMM shrinks to PQ (512 cols), R-plane
//    write + addend read eliminated (~62 MB less traffic).
//  - embed GEMM merged into fold/bias kernel (one fewer dispatch+gap).
// R16 lesson: grid-barrier mega-fusion = per-block L2 flush storms on
// non-coherent XCD L2s (3383us, 2% HBM). Kernel boundaries stay.
// ---------------------------------------------------------------------------

#define HID 256

typedef _Float16 h8 __attribute__((ext_vector_type(8)));
typedef float f32x4 __attribute__((ext_vector_type(4)));

__device__ __forceinline__ void unpack_h8(const int4& r, float* f) {
    const __half2* h = reinterpret_cast<const __half2*>(&r);
#pragma unroll
    for (int k = 0; k < 4; ++k) {
        float2 t = __half22float2(h[k]);
        f[2 * k] = t.x;
        f[2 * k + 1] = t.y;
    }
}

__device__ __forceinline__ void unpack_h4(const int2& r, float* f) {
    const __half2* h = reinterpret_cast<const __half2*>(&r);
    float2 t0 = __half22float2(h[0]);
    float2 t1 = __half22float2(h[1]);
    f[0] = t0.x; f[1] = t0.y; f[2] = t1.x; f[3] = t1.y;
}

// async global -> LDS 16B DMA; dest wave-uniform, lane i lands at dest+16*i
__device__ __forceinline__ void gld16(const void* g, void* l) {
    __builtin_amdgcn_global_load_lds(
        (const __attribute__((address_space(1))) void*)g,
        (__attribute__((address_space(3))) void*)l, 16, 0, 0);
}

// XOR swizzle of 16B k-segments per row; fragment reads <=2-way (free)
__device__ __forceinline__ int swz(int row) { return (row + (row >> 2)) & 3; }

// ------------------------------ CSR build ----------------------------------

__global__ void hist_act_kernel(const int* __restrict__ dst, int* __restrict__ deg,
                                int E, const float* __restrict__ atom,
                                __half* __restrict__ atomH, int NA) {
    int i = blockIdx.x * blockDim.x + threadIdx.x;
    if (i < E) atomicAdd(&deg[dst[i]], 1);
    if (i < NA) {
        int r = i >> 3, seg = i & 7;
        h8 v;
#pragma unroll
        for (int j = 0; j < 8; ++j) {
            int c = seg * 8 + j;
            v[j] = (_Float16)((c < 62) ? atom[(size_t)r * 62 + c] : 0.f);
        }
        *reinterpret_cast<h8*>(&atomH[(size_t)r * 64 + seg * 8]) = v;
    }
}

__global__ __launch_bounds__(256) void scan_kernel(
    const int* __restrict__ deg, int* __restrict__ offs, float* __restrict__ degf, int n) {
    __shared__ int ws[4];
    const int t = threadIdx.x;
    const int lane = t & 63;
    const int w = t >> 6;
    const int per = (n + 255) / 256;
    const int s = t * per;
    const int e = min(s + per, n);
    int sum = 0;
    for (int i = s; i < e; ++i) sum += deg[i];
    int v = sum;
#pragma unroll
    for (int off = 1; off < 64; off <<= 1) {
        int u = __shfl_up(v, off, 64);
        if (lane >= off) v += u;
    }
    if (lane == 63) ws[w] = v;
    __syncthreads();
    if (t == 0) {
        int c = 0;
#pragma unroll
        for (int i = 0; i < 4; ++i) { int x = ws[i]; ws[i] = c; c += x; }
    }
    __syncthreads();
    int run = ws[w] + v - sum;
    for (int i = s; i < e; ++i) {
        int d = deg[i];
        offs[i] = run;
        degf[i] = (float)d;
        run += d;
    }
    if (e == n) offs[n] = run;
}

// ------------------------ weight convert -----------------------------------
// src [Kreal, srcN] fp32 row-major -> dst [srcN][dstStride] fp16 (transposed),
// k range [0, Kpad) written at dst[n*dstStride + k].

struct CDesc {
    const float* src;
    __half* dst;
    int Kreal, Kpad, srcN, tile0, dstStride;
};
struct CTab {
    CDesc d[32];
    int nd;
};

__device__ void convert_body(const CTab& tab, int bid) {
    int idx = 0;
    for (int i = 1; i < tab.nd; ++i)
        if (tab.d[i].tile0 <= bid) idx = i;
    const CDesc d = tab.d[idx];
    const int q = bid - d.tile0;
    const int ntN = d.srcN >> 6;
    const int kb = (q / ntN) * 32;
    const int nb = (q % ntN) * 64;
    const int n = nb + (threadIdx.x & 63);
    const int k0 = kb + (threadIdx.x >> 6) * 8;
    h8 v;
#pragma unroll
    for (int j = 0; j < 8; ++j) {
        int k = k0 + j;
        v[j] = (_Float16)((k < d.Kreal) ? d.src[(size_t)k * d.srcN + n] : 0.f);
    }
    *reinterpret_cast<h8*>(&d.dst[(size_t)n * d.dstStride + k0]) = v;
}

// scatter (CSR fill + ef fp16x8 pack) merged with convert pass 1
__global__ __launch_bounds__(256) void scatter_conv_kernel(
    const int* __restrict__ src, const int* __restrict__ dst,
    const int* __restrict__ offs, int* __restrict__ cursor,
    int* __restrict__ csr_src, const float* __restrict__ ef,
    __half* __restrict__ ef8, int E, int sblocks, CTab tab) {
    if ((int)blockIdx.x < sblocks) {
        int i = blockIdx.x * blockDim.x + threadIdx.x;
        if (i < E) {
            int d = dst[i];
            int pos = atomicAdd(&cursor[d], 1);
            int idx = offs[d] + pos;
            csr_src[idx] = src[i];
            const float* s6 = ef + (size_t)i * 6;
            unsigned short h[8];
#pragma unroll
            for (int j = 0; j < 6; ++j) h[j] = __half_as_ushort(__float2half_rn(s6[j]));
            h[6] = 0; h[7] = 0;
            int4 pk;
            pk.x = (int)(h[0] | ((unsigned)h[1] << 16));
            pk.y = (int)(h[2] | ((unsigned)h[3] << 16));
            pk.z = (int)(h[4] | ((unsigned)h[5] << 16));
            pk.w = (int)(h[6] | ((unsigned)h[7] << 16));
            *reinterpret_cast<int4*>(ef8 + (size_t)idx * 8) = pk;
        }
    } else {
        convert_body(tab, blockIdx.x - sblocks);
    }
}

// ----------------------- folded bias vectors -------------------------------
// out[j] = base[j] + v1.B1[:,j] + v2.B2[:,j]; all-null => 0 (zero-fill).

struct BDesc { float* out; const float* base; const float* v1; const float* B1;
               const float* v2; const float* B2; };
struct BTab { BDesc d[31]; };

// ------------------- batched fold GEMM tile --------------------------------
// Computes M^T[n][k] = sum_j fb[n][j] * U2[k][j]  (= (U2@W)[k][n]) and writes
// the fp16 [n][k] GEMM weight plane DIRECTLY at dst[n*stride + k].

#define ASTR 40

struct FDesc { const float* U2; const __half* Wfb; __half* dst; int stride; };
struct FTab { FDesc d[22]; };

__device__ void fold_tile(unsigned char* ldsraw, const FDesc& dd, int t4) {
    _Float16* Ah = (_Float16*)ldsraw;                       // fb rows (n)
    _Float16* Bh = (_Float16*)(ldsraw + 64 * ASTR * 2);     // U2 rows (k)
    const int rowBase = (t4 >> 2) * 64;  // n-block
    const int colBase = (t4 & 3) * 64;   // k-block

    const int tid = threadIdx.x;
    const int lane = tid & 63;
    const int wave = tid >> 6;
    const int waveM = (wave >> 1) * 32;
    const int waveN = (wave & 1) * 32;
    const int m0 = lane & 15;
    const int quad = lane >> 4;
    const int sr = tid >> 2;
    const int sseg = tid & 3;

    const f32x4 z = {0.f, 0.f, 0.f, 0.f};
    f32x4 acc[2][2] = {{z, z}, {z, z}};

    for (int kb = 0; kb < 256; kb += 32) {
        {
            size_t off = (size_t)(rowBase + sr) * 256 + kb + sseg * 8;
            *reinterpret_cast<int4*>(&Ah[sr * ASTR + sseg * 8]) =
                *reinterpret_cast<const int4*>(&dd.Wfb[off]);
        }
        {
            const float* Bp = dd.U2 + (size_t)(colBase + sr) * 256 + kb + sseg * 8;
            float4 u0 = *reinterpret_cast<const float4*>(Bp);
            float4 u1 = *reinterpret_cast<const float4*>(Bp + 4);
            h8 v;
            v[0] = (_Float16)u0.x; v[1] = (_Float16)u0.y;
            v[2] = (_Float16)u0.z; v[3] = (_Float16)u0.w;
            v[4] = (_Float16)u1.x; v[5] = (_Float16)u1.y;
            v[6] = (_Float16)u1.z; v[7] = (_Float16)u1.w;
            *reinterpret_cast<h8*>(&Bh[sr * ASTR + sseg * 8]) = v;
        }
        __syncthreads();

        const h8 a0 = *reinterpret_cast<const h8*>(&Ah[(waveM + m0) * ASTR + quad * 8]);
        const h8 a1 = *reinterpret_cast<const h8*>(&Ah[(waveM + 16 + m0) * ASTR + quad * 8]);
        const h8 b0 = *reinterpret_cast<const h8*>(&Bh[(waveN + m0) * ASTR + quad * 8]);
        const h8 b1 = *reinterpret_cast<const h8*>(&Bh[(waveN + 16 + m0) * ASTR + quad * 8]);

        acc[0][0] = __builtin_amdgcn_mfma_f32_16x16x32_f16(a0, b0, acc[0][0], 0, 0, 0);
        acc[0][1] = __builtin_amdgcn_mfma_f32_16x16x32_f16(a0, b1, acc[0][1], 0, 0, 0);
        acc[1][0] = __builtin_amdgcn_mfma_f32_16x16x32_f16(a1, b0, acc[1][0], 0, 0, 0);
        acc[1][1] = __builtin_amdgcn_mfma_f32_16x16x32_f16(a1, b1, acc[1][1], 0, 0, 0);

        __syncthreads();
    }

#pragma unroll
    for (int tm = 0; tm < 2; ++tm)
#pragma unroll
        for (int reg = 0; reg < 4; ++reg) {
            int n = rowBase + waveM + tm * 16 + quad * 4 + reg;
#pragma unroll
            for (int tn = 0; tn < 2; ++tn) {
                int k = colBase + waveN + tn * 16 + m0;
                dd.dst[(size_t)n * dd.stride + k] = __float2half_rn(acc[tm][tn][reg]);
            }
        }
}

// ------------------------------ MFMA GEMM tile -----------------------------
// C = act( [A|A2]@W + bias + rowscale.*bias2 ), fp16 in/out, fp32 acc.
// A covers k<256, A2 (optional) covers k>=256 (both row-stride lda).
// Tile 64 x (TN*32), BK=32, 4 waves 2x2. Double-buffered K-loop:
// raw s_barrier + manual vmcnt (block-uniform).

template <int TN>
__device__ void gemm_tile(
    unsigned char* lds, int bx, int by,
    const __half* __restrict__ A, int lda, const __half* __restrict__ A2,
    const __half* __restrict__ W, int K,
    const float* __restrict__ bias, const float* __restrict__ bias2,
    const float* __restrict__ rowscale,
    __half* __restrict__ C, int M, int Nc, int do_relu) {
    constexpr int BUF = 4096 + TN * 2048;  // bytes per buffer set

    const int tid = threadIdx.x;
    const int lane = tid & 63;
    const int wave = tid >> 6;
    const int m0 = lane & 15;
    const int quad = lane >> 4;
    const int waveM = (wave >> 1) * 32;
    const int waveN = (wave & 1) * (TN * 16);
    const int rowBase = bx * 64;
    const int colBase = by * (TN * 32);

    const int sa_r = tid >> 2;
    const int sa_ks = (tid & 3) ^ swz(sa_r);
    const int sa_row = min(rowBase + sa_r, M - 1);
    const int sb_r1 = sa_r + 64;
    const int sb_ks1 = (tid & 3) ^ swz(sb_r1);

    int aoff[2], boff[TN];
#pragma unroll
    for (int tm = 0; tm < 2; ++tm) {
        int r = waveM + tm * 16 + m0;
        aoff[tm] = ((r << 2) + (quad ^ swz(r))) << 4;
    }
#pragma unroll
    for (int tn = 0; tn < TN; ++tn) {
        int r = waveN + tn * 16 + m0;
        boff[tn] = 4096 + (((r << 2) + (quad ^ swz(r))) << 4);
    }

    const f32x4 z = {0.f, 0.f, 0.f, 0.f};
    f32x4 acc[2][TN];
#pragma unroll
    for (int tm = 0; tm < 2; ++tm)
#pragma unroll
        for (int tn = 0; tn < TN; ++tn) acc[tm][tn] = z;

    const __half* ga = A + (size_t)sa_row * lda + sa_ks * 8;
    const __half* ga2 = A2 ? A2 + (size_t)sa_row * lda + sa_ks * 8 : nullptr;
    const __half* gb0 = W + (size_t)(colBase + sa_r) * K + sa_ks * 8;
    const __half* gb1 = W + (size_t)(colBase + sb_r1) * K + sb_ks1 * 8;

    auto issue = [&](int p, int kb) {
        unsigned char* base = lds + p * BUF;
        const __half* as = (A2 && kb >= 256) ? (ga2 + (kb - 256)) : (ga + kb);
        gld16(as, base + wave * 1024);
        gld16(gb0 + kb, base + 4096 + wave * 1024);
        if constexpr (TN == 4) gld16(gb1 + kb, base + 8192 + wave * 1024);
    };

    issue(0, 0);
    int p = 0;
    for (int kb = 0; kb < K; kb += 32) {
        const bool has_next = (kb + 32 < K);
        if (has_next) issue(p ^ 1, kb + 32);
        if (has_next) {
            if constexpr (TN == 4)
                asm volatile("s_waitcnt vmcnt(3)" ::: "memory");
            else
                asm volatile("s_waitcnt vmcnt(2)" ::: "memory");
        } else {
            asm volatile("s_waitcnt vmcnt(0)" ::: "memory");
        }
        asm volatile("s_barrier" ::: "memory");

        const unsigned char* base = lds + p * BUF;
        h8 ah[2], bh[TN];
#pragma unroll
        for (int tm = 0; tm < 2; ++tm)
            ah[tm] = *reinterpret_cast<const h8*>(base + aoff[tm]);
#pragma unroll
        for (int tn = 0; tn < TN; ++tn)
            bh[tn] = *reinterpret_cast<const h8*>(base + boff[tn]);
#pragma unroll
        for (int tm = 0; tm < 2; ++tm)
#pragma unroll
            for (int tn = 0; tn < TN; ++tn)
                acc[tm][tn] = __builtin_amdgcn_mfma_f32_16x16x32_f16(
                    ah[tm], bh[tn], acc[tm][tn], 0, 0, 0);
        asm volatile("s_waitcnt lgkmcnt(0)" ::: "memory");
        asm volatile("s_barrier" ::: "memory");
        p ^= 1;
    }

    // epilogue
    float cb[TN], db[TN];
    int col[TN];
#pragma unroll
    for (int tn = 0; tn < TN; ++tn) {
        col[tn] = colBase + waveN + tn * 16 + m0;
        cb[tn] = bias ? bias[col[tn]] : 0.f;
        db[tn] = bias2 ? bias2[col[tn]] : 0.f;
    }
#pragma unroll
    for (int tm = 0; tm < 2; ++tm) {
#pragma unroll
        for (int reg = 0; reg < 4; ++reg) {
            int row = rowBase + waveM + tm * 16 + quad * 4 + reg;
            if (row >= M) continue;
            float rs = rowscale ? rowscale[row] : 0.0f;
#pragma unroll
            for (int tn = 0; tn < TN; ++tn) {
                float v = acc[tm][tn][reg] + cb[tn] + rs * db[tn];
                if (do_relu) v = fmaxf(v, 0.f);
                C[(size_t)row * Nc + col[tn]] = __float2half_rn(v);
            }
        }
    }
}

template <int TN>
__global__ __launch_bounds__(256) void mfma_gemm(
    const __half* __restrict__ A, int lda, const __half* __restrict__ A2,
    const __half* __restrict__ W, int K,
    const float* __restrict__ bias, const float* __restrict__ bias2,
    const float* __restrict__ rowscale,
    __half* __restrict__ C, int M, int Nc, int do_relu) {
    __shared__ __align__(16) unsigned char lds[2 * (4096 + TN * 2048)];
    gemm_tile<TN>(lds, blockIdx.x, blockIdx.y, A, lda, A2, W, K,
                  bias, bias2, rowscale, C, M, Nc, do_relu);
}

// -------------------- fold GEMMs + bias vecs + embed -----------------------
// Independent setup work sharing one dispatch: fold tiles, bias vectors, and
// the embed GEMM (U0 = atomH @ w_emb + emb_b).

__global__ __launch_bounds__(256) void fold_bias_embed_kernel(
    FTab ft, BTab bt, int fblocks, int bblocks,
    const __half* __restrict__ atomH, const __half* __restrict__ w_emb,
    const float* __restrict__ emb_b, __half* __restrict__ outX,
    int M, int mblk) {
    __shared__ __align__(16) unsigned char lds[16384];
    int b = blockIdx.x;
    if (b < fblocks) {
        fold_tile(lds, ft.d[b >> 4], b & 15);
        return;
    }
    b -= fblocks;
    if (b < bblocks) {
        const BDesc d = bt.d[b];
        const int j = threadIdx.x;
        float acc = d.base ? d.base[j] : 0.f;
        if (d.v1)
            for (int k = 0; k < 256; ++k) acc = fmaf(d.v1[k], d.B1[(size_t)k * 256 + j], acc);
        if (d.v2)
            for (int k = 0; k < 256; ++k) acc = fmaf(d.v2[k], d.B2[(size_t)k * 256 + j], acc);
        d.out[j] = acc;
        return;
    }
    b -= bblocks;
    gemm_tile<2>(lds, b % mblk, b / mblk, atomH, 64, nullptr, w_emb, 64,
                 emb_b, nullptr, nullptr, outX, M, HID, 0);
}

// --------------------------- edge aggregation ------------------------------
// Hagg[v] = sum_{e=(s,v)} relu(P[s] + Q[v] + ef_e @ W1c); bagg pre-added to
// Q by the PQ GEMM bias. PQ fp16 [N][512]. One wave/node; full wave per edge
// (4 channels/lane) for low VGPR -> high occupancy; 6-edge batches.

__global__ __launch_bounds__(256) void aggregate_kernel(
    const __half* __restrict__ PQ, const __half* __restrict__ ef8,
    const int* __restrict__ offs, const int* __restrict__ csr_src,
    const float* __restrict__ W1c, __half* __restrict__ Hagg, int n) {
    const int wave = threadIdx.x >> 6;
    const int lane = threadIdx.x & 63;
    const int node = blockIdx.x * 4 + wave;
    if (node >= n) return;
    const int ch = lane * 4;  // 64 lanes x 4 ch = 256

    float wc[6][4];
#pragma unroll
    for (int k = 0; k < 6; ++k) {
        float4 w0 = *reinterpret_cast<const float4*>(W1c + k * HID + ch);
        wc[k][0] = w0.x; wc[k][1] = w0.y; wc[k][2] = w0.z; wc[k][3] = w0.w;
    }
    float qb[4];
    unpack_h4(*reinterpret_cast<const int2*>(PQ + (size_t)node * 512 + 256 + ch), qb);

    float acc[4] = {0.f, 0.f, 0.f, 0.f};

    auto fma_edge = [&](const int2& praw, const int4& eraw) {
        float p[4], e[8];
        unpack_h4(praw, p);
        unpack_h8(eraw, e);
#pragma unroll
        for (int i = 0; i < 4; ++i) {
            float h = p[i] + qb[i];
            h = fmaf(e[0], wc[0][i], h);
            h = fmaf(e[1], wc[1][i], h);
            h = fmaf(e[2], wc[2][i], h);
            h = fmaf(e[3], wc[3][i], h);
            h = fmaf(e[4], wc[4][i], h);
            h = fmaf(e[5], wc[5][i], h);
            acc[i] += fmaxf(h, 0.f);
        }
    };

    const int beg = offs[node];
    const int end = offs[node + 1];
    int j = beg;

    // main loop: 6 edges per batch, all loads issued upfront
    while (j + 6 <= end) {
        int s0 = csr_src[j];
        int s1 = csr_src[j + 1];
        int s2 = csr_src[j + 2];
        int s3 = csr_src[j + 3];
        int s4 = csr_src[j + 4];
        int s5 = csr_src[j + 5];
        int4 e0 = *reinterpret_cast<const int4*>(ef8 + (size_t)j * 8);
        int4 e1 = *reinterpret_cast<const int4*>(ef8 + (size_t)(j + 1) * 8);
        int4 e2 = *reinterpret_cast<const int4*>(ef8 + (size_t)(j + 2) * 8);
        int4 e3 = *reinterpret_cast<const int4*>(ef8 + (size_t)(j + 3) * 8);
        int4 e4 = *reinterpret_cast<const int4*>(ef8 + (size_t)(j + 4) * 8);
        int4 e5 = *reinterpret_cast<const int4*>(ef8 + (size_t)(j + 5) * 8);
        int2 p0 = *reinterpret_cast<const int2*>(PQ + (size_t)s0 * 512 + ch);
        int2 p1 = *reinterpret_cast<const int2*>(PQ + (size_t)s1 * 512 + ch);
        int2 p2 = *reinterpret_cast<const int2*>(PQ + (size_t)s2 * 512 + ch);
        int2 p3 = *reinterpret_cast<const int2*>(PQ + (size_t)s3 * 512 + ch);
        int2 p4 = *reinterpret_cast<const int2*>(PQ + (size_t)s4 * 512 + ch);
        int2 p5 = *reinterpret_cast<const int2*>(PQ + (size_t)s5 * 512 + ch);
        fma_edge(p0, e0);
        fma_edge(p1, e1);
        fma_edge(p2, e2);
        fma_edge(p3, e3);
        fma_edge(p4, e4);
        fma_edge(p5, e5);
        j += 6;
    }
    // paired tail (2 gathers in flight)
    while (j + 2 <= end) {
        int s0 = csr_src[j];
        int s1 = csr_src[j + 1];
        int4 e0 = *reinterpret_cast<const int4*>(ef8 + (size_t)j * 8);
        int4 e1 = *reinterpret_cast<const int4*>(ef8 + (size_t)(j + 1) * 8);
        int2 p0 = *reinterpret_cast<const int2*>(PQ + (size_t)s0 * 512 + ch);
        int2 p1 = *reinterpret_cast<const int2*>(PQ + (size_t)s1 * 512 + ch);
        fma_edge(p0, e0);
        fma_edge(p1, e1);
        j += 2;
    }
    if (j < end) {
        int s = csr_src[j];
        int4 e = *reinterpret_cast<const int4*>(ef8 + (size_t)j * 8);
        int2 pw = *reinterpret_cast<const int2*>(PQ + (size_t)s * 512 + ch);
        fma_edge(pw, e);
    }

    unsigned short hs[4];
#pragma unroll
    for (int i = 0; i < 4; ++i) hs[i] = __half_as_ushort(__float2half_rn(acc[i]));
    int2 pk;
    pk.x = (int)(hs[0] | ((unsigned)hs[1] << 16));
    pk.y = (int)(hs[2] | ((unsigned)hs[3] << 16));
    *reinterpret_cast<int2*>(Hagg + (size_t)node * HID + ch) = pk;
}

// --------------------------- fused readout ---------------------------------
// h1 = relu(U5@wF + cbF) -> LDS (stride 272 halves); h2 = relu(h1@wR2 + bR2);
// s += h2 . w3 per row; block reduce; atomicAdd; done-counter finalize.

__global__ __launch_bounds__(256) void readout_kernel(
    const __half* __restrict__ U5, const __half* __restrict__ wF,
    const float* __restrict__ cbF, const __half* __restrict__ wR2,
    const float* __restrict__ bR2, const float* __restrict__ w3,
    const float* __restrict__ b3, float* __restrict__ accum,
    int* __restrict__ done, float* __restrict__ outp, int M, int nblocks) {
    __shared__ __align__(16) unsigned char lds[24576 + 64 * 272 * 2];
    _Float16* h1 = (_Float16*)(lds + 24576);

    const int tid = threadIdx.x;
    const int lane = tid & 63;
    const int wave = tid >> 6;
    const int m0 = lane & 15;
    const int quad = lane >> 4;
    const int waveM = (wave >> 1) * 32;
    const int waveN = (wave & 1) * 64;
    const int rowBase = blockIdx.x * 64;

    const int sa_r = tid >> 2;
    const int sa_ks = (tid & 3) ^ swz(sa_r);
    const int sa_row = min(rowBase + sa_r, M - 1);
    const int sb_r1 = sa_r + 64;
    const int sb_ks1 = (tid & 3) ^ swz(sb_r1);

    int aoff[2], boff[4];
#pragma unroll
    for (int tm = 0; tm < 2; ++tm) {
        int r = waveM + tm * 16 + m0;
        aoff[tm] = ((r << 2) + (quad ^ swz(r))) << 4;
    }
#pragma unroll
    for (int tn = 0; tn < 4; ++tn) {
        int r = waveN + tn * 16 + m0;
        boff[tn] = (((r << 2) + (quad ^ swz(r))) << 4);
    }

    constexpr int BUF = 4096 + 4 * 2048;
    const f32x4 z = {0.f, 0.f, 0.f, 0.f};

    for (int half = 0; half < 2; ++half) {
        const __half* W = wF + (size_t)(half * 128) * 256;
        f32x4 acc[2][4] = {{z, z, z, z}, {z, z, z, z}};
        const __half* ga = U5 + (size_t)sa_row * 256 + sa_ks * 8;
        const __half* gb0 = W + (size_t)sa_r * 256 + sa_ks * 8;
        const __half* gb1 = W + (size_t)sb_r1 * 256 + sb_ks1 * 8;

        auto issue = [&](int p, int kb) {
            unsigned char* base = lds + p * BUF;
            gld16(ga + kb, base + wave * 1024);
            gld16(gb0 + kb, base + 4096 + wave * 1024);
            gld16(gb1 + kb, base + 8192 + wave * 1024);
        };
        issue(0, 0);
        int p = 0;
        for (int kb = 0; kb < 256; kb += 32) {
            const bool has_next = (kb + 32 < 256);
            if (has_next) issue(p ^ 1, kb + 32);
            if (has_next) asm volatile("s_waitcnt vmcnt(3)" ::: "memory");
            else asm volatile("s_waitcnt vmcnt(0)" ::: "memory");
            asm volatile("s_barrier" ::: "memory");
            const unsigned char* base = lds + p * BUF;
            h8 ah[2], bh[4];
#pragma unroll
            for (int tm = 0; tm < 2; ++tm)
                ah[tm] = *reinterpret_cast<const h8*>(base + aoff[tm]);
#pragma unroll
            for (int tn = 0; tn < 4; ++tn)
                bh[tn] = *reinterpret_cast<const h8*>(base + 4096 + boff[tn]);
#pragma unroll
            for (int tm = 0; tm < 2; ++tm)
#pragma unroll
                for (int tn = 0; tn < 4; ++tn)
                    acc[tm][tn] = __builtin_amdgcn_mfma_f32_16x16x32_f16(
                        ah[tm], bh[tn], acc[tm][tn], 0, 0, 0);
            asm volatile("s_waitcnt lgkmcnt(0)" ::: "memory");
            asm volatile("s_barrier" ::: "memory");
            p ^= 1;
        }
#pragma unroll
        for (int tm = 0; tm < 2; ++tm)
#pragma unroll
            for (int reg = 0; reg < 4; ++reg) {
                int r = waveM + tm * 16 + quad * 4 + reg;
#pragma unroll
                for (int tn = 0; tn < 4; ++tn) {
                    int c = half * 128 + waveN + tn * 16 + m0;
                    float v = acc[tm][tn][reg] + cbF[c];
                    h1[r * 272 + c] = (_Float16)fmaxf(v, 0.f);
                }
            }
        __syncthreads();
    }

    f32x4 acc2[2][4] = {{z, z, z, z}, {z, z, z, z}};
    auto issueB = [&](int p, int kb) {
        unsigned char* base = lds + p * 8192;
        gld16(wR2 + (size_t)sa_r * 256 + sa_ks * 8 + kb, base + wave * 1024);
        gld16(wR2 + (size_t)sb_r1 * 256 + sb_ks1 * 8 + kb, base + 4096 + wave * 1024);
    };
    issueB(0, 0);
    int p = 0;
    for (int kb = 0; kb < 256; kb += 32) {
        const bool has_next = (kb + 32 < 256);
        if (has_next) issueB(p ^ 1, kb + 32);
        if (has_next) asm volatile("s_waitcnt vmcnt(2)" ::: "memory");
        else asm volatile("s_waitcnt vmcnt(0)" ::: "memory");
        asm volatile("s_barrier" ::: "memory");
        const unsigned char* base = lds + p * 8192;
        h8 ah[2], bh[4];
#pragma unroll
        for (int tm = 0; tm < 2; ++tm)
            ah[tm] = *reinterpret_cast<const h8*>(
                &h1[(waveM + tm * 16 + m0) * 272 + kb + quad * 8]);
#pragma unroll
        for (int tn = 0; tn < 4; ++tn)
            bh[tn] = *reinterpret_cast<const h8*>(base + boff[tn]);
#pragma unroll
        for (int tm = 0; tm < 2; ++tm)
#pragma unroll
            for (int tn = 0; tn < 4; ++tn)
                acc2[tm][tn] = __builtin_amdgcn_mfma_f32_16x16x32_f16(
                    ah[tm], bh[tn], acc2[tm][tn], 0, 0, 0);
        asm volatile("s_waitcnt lgkmcnt(0)" ::: "memory");
        asm volatile("s_barrier" ::: "memory");
        p ^= 1;
    }

    float s = 0.f;
#pragma unroll
    for (int tm = 0; tm < 2; ++tm)
#pragma unroll
        for (int reg = 0; reg < 4; ++reg) {
            int row = rowBase + waveM + tm * 16 + quad * 4 + reg;
            if (row >= M) continue;
#pragma unroll
            for (int tn = 0; tn < 4; ++tn) {
                int c = waveN + tn * 16 + m0;
                float v = acc2[tm][tn][reg] + bR2[c];
                s += fmaxf(v, 0.f) * w3[c];
            }
        }
    __syncthreads();
    float* red = (float*)lds;
    red[tid] = s;
    __syncthreads();
    for (int off = 128; off > 0; off >>= 1) {
        if (tid < off) red[tid] += red[tid + off];
        __syncthreads();
    }
    if (tid == 0) {
        atomicAdd(accum, red[0]);
        __threadfence();
        int old = atomicAdd(done, 1);
        if (old == nblocks - 1) {
            float tot = atomicAdd(accum, 0.0f);
            outp[0] = tot / (float)M + b3[0];
        }
    }
}

// ------------------------------- driver ------------------------------------

extern "C" void kernel_launch(void* const* d_in, const int* in_sizes, int n_in,
                              void* d_out, int out_size, void* d_ws, size_t ws_size,
                              hipStream_t stream) {
    const float* atom   = (const float*)d_in[0];
    const int*   eidx   = (const int*)d_in[1];
    const float* ef     = (const float*)d_in[2];
    const float* emb_w  = (const float*)d_in[3];
    const float* emb_b  = (const float*)d_in[4];
    const float* msg_w1 = (const float*)d_in[5];
    const float* msg_b1 = (const float*)d_in[6];
    const float* msg_w2 = (const float*)d_in[7];
    const float* msg_b2 = (const float*)d_in[8];
    const float* upd_w1 = (const float*)d_in[9];
    const float* upd_b1 = (const float*)d_in[10];
    const float* upd_w2 = (const float*)d_in[11];
    const float* upd_b2 = (const float*)d_in[12];
    const float* r_w1   = (const float*)d_in[13];
    const float* r_b1   = (const float*)d_in[14];
    const float* r_w2   = (const float*)d_in[15];
    const float* r_b2   = (const float*)d_in[16];
    const float* r_w3   = (const float*)d_in[17];
    const float* r_b3   = (const float*)d_in[18];

    const int N = in_sizes[0] / 62;
    const int E = in_sizes[1] / 2;
    const int L = in_sizes[5] / (518 * 256);
    const int* src = eidx;
    const int* dst = eidx + E;

    char* wp = (char*)d_ws;
    auto alloc = [&](size_t bytes) -> void* {
        void* p = (void*)wp;
        wp += (bytes + 255) & ~(size_t)255;
        return p;
    };
    int*   deg     = (int*)alloc((size_t)N * 4);
    int*   cursor  = (int*)alloc((size_t)N * 4);
    float* accum   = (float*)alloc(256);
    int*   done    = (int*)((char*)accum + 16);
    size_t zero_bytes = (size_t)((char*)accum - (char*)d_ws) + 256;
    float* degf    = (float*)alloc((size_t)N * 4);
    int*   offs    = (int*)alloc((size_t)(N + 1) * 4);
    int*   csr_src = (int*)alloc((size_t)E * 4);
    __half* ef8    = (__half*)alloc((size_t)E * 8 * 2);

    const int SQ_P = 256 * 256;
    __half* w_emb = (__half*)alloc((size_t)256 * 64 * 2);
    __half* w_r2  = (__half*)alloc((size_t)128 * 256 * 2);
    __half* wF    = (__half*)alloc((size_t)SQ_P * 2);
    __half *wPQ[6], *wUPD[6];
    for (int l = 0; l < L; ++l) {
        wPQ[l]  = (__half*)alloc((size_t)512 * 256 * 2);  // [512 cols][K=256]
        wUPD[l] = (__half*)alloc((size_t)256 * 512 * 2);  // [256 cols][K=512] = [wM3;wR]
    }
    __half* fb[22];
    for (int i = 0; i < 22; ++i) fb[i] = (__half*)alloc((size_t)SQ_P * 2);
    float* bvec = (float*)alloc((size_t)19 * 256 * 4);
    float* b512 = (float*)alloc((size_t)L * 512 * 4);

    __half* atomH = (__half*)alloc((size_t)N * 64 * 2);
    __half* bufX0 = (__half*)alloc((size_t)N * HID * 2);
    __half* bufX1 = (__half*)alloc((size_t)N * HID * 2);
    __half* PQ    = (__half*)alloc((size_t)N * 512 * 2);
    __half* HaggH = (__half*)alloc((size_t)N * HID * 2);

    hipMemsetAsync(d_ws, 0, zero_bytes, stream);

    // ---- CSR build + atom convert ----
    const int hag = max(E, N * 8);
    hist_act_kernel<<<(hag + 255) / 256, 256, 0, stream>>>(dst, deg, E, atom, atomH, N * 8);
    scan_kernel<<<1, 256, 0, stream>>>(deg, offs, degf, N);

    // ---- convert pass 1 descriptors (direct-use weights + fold B-operands) ----
    CTab ct1;
    int nd = 0, tiles = 0;
    auto addDesc = [&](const float* s, __half* dh, int Kreal, int Kpad, int srcN,
                       int dstStride) {
        ct1.d[nd] = {s, dh, Kreal, Kpad, srcN, tiles, dstStride};
        tiles += (Kpad / 32) * (srcN / 64);
        ++nd;
    };
    addDesc(emb_w, w_emb, 62, 64, 256, 64);
    addDesc(msg_w1, wPQ[0], 256, 256, 256, 256);                  // P plane l=0
    addDesc(msg_w1 + 256 * 256, wPQ[0] + SQ_P, 256, 256, 256, 256);  // Q plane l=0
    addDesc(upd_w1, wUPD[0] + 256, 256, 256, 256, 512);           // R plane l=0 -> wUPD hi-K
    addDesc(r_w2, w_r2, 256, 256, 128, 256);
    for (int l = 1; l < L; ++l) {
        addDesc(msg_w1 + (size_t)l * 518 * 256,             fb[l - 1], 256, 256, 256, 256);
        addDesc(msg_w1 + (size_t)l * 518 * 256 + 256 * 256, fb[4 + l], 256, 256, 256, 256);
        addDesc(upd_w1 + (size_t)l * 512 * 256,             fb[9 + l], 256, 256, 256, 256);
    }
    for (int l = 0; l < L; ++l)
        addDesc(upd_w1 + (size_t)l * 512 * 256 + 256 * 256, fb[15 + l], 256, 256, 256, 256);
    addDesc(r_w1, fb[21], 256, 256, 256, 256);
    ct1.nd = nd;

    // scatter + convert1 merged (one launch)
    const int sblocks = (E + 255) / 256;
    scatter_conv_kernel<<<sblocks + tiles, 256, 0, stream>>>(
        src, dst, offs, cursor, csr_src, ef, ef8, E, sblocks, ct1);

    // ---- fold GEMMs + bias vecs + embed merged ----
    FTab ft;
    for (int l = 1; l < L; ++l) {
        const float* U2p = upd_w2 + (size_t)(l - 1) * SQ_P;
        ft.d[l - 1] = {U2p, fb[l - 1], wPQ[l], 256};          // P plane
        ft.d[4 + l] = {U2p, fb[4 + l], wPQ[l] + SQ_P, 256};   // Q plane
        ft.d[9 + l] = {U2p, fb[9 + l], wUPD[l] + 256, 512};   // R plane -> wUPD hi-K
    }
    for (int l = 0; l < L; ++l)
        ft.d[15 + l] = {msg_w2 + (size_t)l * SQ_P, fb[15 + l], wUPD[l], 512};  // M3 plane
    ft.d[21] = {upd_w2 + (size_t)5 * SQ_P, fb[21], wF, 256};

    BTab bt;
    int nb = 0;
    for (int l = 0; l < L; ++l) {
        const float* ub2p = (l > 0) ? upd_b2 + (size_t)(l - 1) * 256 : nullptr;
        // b512[l] = [0 | bagg]
        bt.d[nb++] = {b512 + (size_t)l * 512 + 256, msg_b1 + (size_t)l * 256,
                      ub2p, msg_w1 + (size_t)l * 518 * 256,
                      ub2p, msg_w1 + (size_t)l * 518 * 256 + 256 * 256};
        bt.d[nb++] = {b512 + (size_t)l * 512, nullptr, nullptr, nullptr, nullptr, nullptr};
        bt.d[nb++] = {bvec + (size_t)(6 + l) * 256, upd_b1 + (size_t)l * 256,
                      ub2p, upd_w1 + (size_t)l * 512 * 256, nullptr, nullptr};
        bt.d[nb++] = {bvec + (size_t)(12 + l) * 256, nullptr,
                      msg_b2 + (size_t)l * 256, upd_w1 + (size_t)l * 512 * 256 + 256 * 256,
                      nullptr, nullptr};
    }
    bt.d[nb++] = {bvec + (size_t)18 * 256, r_b1, upd_b2 + (size_t)5 * 256, r_w1,
                  nullptr, nullptr};

    const int mblk = (N + 63) / 64;
    const int fblocks = 22 * 16;
    fold_bias_embed_kernel<<<fblocks + nb + mblk * 4, 256, 0, stream>>>(
        ft, bt, fblocks, nb, atomH, w_emb, emb_b, bufX0, N, mblk);

    dim3 blk(256);
    __half* U_prev = bufX0;
    __half* U_next = bufX1;
    for (int l = 0; l < L; ++l) {
        const float* w1c = msg_w1 + (size_t)l * 518 * 256 + 512 * 256;

        // PQ = U_prev @ [M1a|M1b] + [0|bagg]   (512 cols)
        mfma_gemm<4><<<dim3(mblk, 4), blk, 0, stream>>>(
            U_prev, HID, nullptr, wPQ[l], HID,
            b512 + (size_t)l * 512, nullptr, nullptr,
            PQ, N, 512, 0);
        aggregate_kernel<<<(N + 3) / 4, blk, 0, stream>>>(
            PQ, ef8, offs, csr_src, w1c, HaggH, N);
        // U_next = relu([Hagg|U_prev] @ [wM3;wR] + b + deg.*b2)   (K=512)
        mfma_gemm<2><<<dim3(mblk, 4), blk, 0, stream>>>(
            HaggH, HID, U_prev, wUPD[l], 512,
            bvec + (size_t)(6 + l) * 256, bvec + (size_t)(12 + l) * 256, degf,
            U_next, N, HID, 1);
        __half* t = U_prev; U_prev = U_next; U_next = t;
    }

    // fused readout (h1 -> h2 -> dot -> finalize)
    readout_kernel<<<mblk, blk, 0, stream>>>(
        U_prev, wF, bvec + (size_t)18 * 256, w_r2, r_b2, r_w3, r_b3,
        accum, done, (float*)d_out, N, mblk);
}